// Round 10
// baseline (138.682 us; speedup 1.0000x reference)
//
#include <hip/hip_runtime.h>
#include <hip/hip_bf16.h>

// Problem constants
#define HB 2
#define HS 2048
#define HH 16
#define HD 64
#define HIDN 1024
#define MROWS 4096   // B*S

typedef __attribute__((ext_vector_type(8))) short s16x8;   // 8 bf16 (4 VGPRs)
typedef __attribute__((ext_vector_type(4))) float f32x4;   // MFMA accumulator
typedef unsigned short u16;

__device__ inline u16 f2bf(float f) {
  union { __hip_bfloat16 h; u16 u; } cvt;
  cvt.h = __float2bfloat16(f);
  return cvt.u;
}

// async global->LDS DMA, 16B per lane. lds base must be wave-uniform;
// lane i lands at base + i*16B. global addr is per-lane.
__device__ __forceinline__ void gload16(const u16* g, u16* l) {
  __builtin_amdgcn_global_load_lds((const __attribute__((address_space(1))) void*)g,
                                   (__attribute__((address_space(3))) void*)l, 16, 0, 0);
}

// ---------------- K0a: fp32 -> bf16 convert (hidden_states) ----------------
__global__ __launch_bounds__(256) void k_cvt(const float* __restrict__ in, u16* __restrict__ out, int n) {
  int i = (blockIdx.x * 256 + threadIdx.x) * 4;
  if (i >= n) return;
  float4 a = *(const float4*)(in + i);
  ushort4 r;
  r.x = f2bf(a.x); r.y = f2bf(a.y); r.z = f2bf(a.z); r.w = f2bf(a.w);
  *(ushort4*)(out + i) = r;
}

// ---------------- K0b: weight transpose fp32[K][C] -> bf16[C][K] -----------
__global__ __launch_bounds__(256) void k_transpose(const float* __restrict__ W0, const float* __restrict__ W1,
                                                   const float* __restrict__ W2, const float* __restrict__ W3,
                                                   u16* __restrict__ out) {
  const float* W = (blockIdx.z == 0) ? W0 : (blockIdx.z == 1) ? W1 : (blockIdx.z == 2) ? W2 : W3;
  u16* O = out + (size_t)blockIdx.z * HIDN * HIDN;
  __shared__ float tile[64][65];
  int k0 = blockIdx.y * 64, c0 = blockIdx.x * 64;
  #pragma unroll
  for (int i = 0; i < 16; ++i) {
    int id = threadIdx.x + i * 256;
    int r = id >> 6, c = id & 63;
    tile[r][c] = W[(size_t)(k0 + r) * HIDN + c0 + c];
  }
  __syncthreads();
  #pragma unroll
  for (int i = 0; i < 16; ++i) {
    int id = threadIdx.x + i * 256;
    int r = id >> 6, c = id & 63;
    O[(size_t)(c0 + r) * HIDN + k0 + c] = f2bf(tile[c][r]);
  }
}

// ---------------- K1: QKV GEMM + info add + RoPE epilogue -------------------
// XCD-aware 1-D grid (768 blocks): XCD g owns m-tiles 4g..4g+3 (A-panels stay
// L2-resident); n fastest (B-panel 2MB/z L2-resident); z outermost.
#define BM 128
#define BN 128
#define BK 64
#define LDK 72   // padded stride for k_attn LDS tiles (16B-aligned rows)

__global__ __launch_bounds__(256) void k_qkv(const u16* __restrict__ X, const u16* __restrict__ Wt,
                                             const float* __restrict__ info,
                                             u16* __restrict__ Qb, u16* __restrict__ Kb, u16* __restrict__ Vt) {
  __shared__ __align__(16) u16 smem[128 * 136];
  const int bid = blockIdx.x;
  const int g   = bid & 7;          // XCD (bid%8 round-robin)
  const int idx = bid >> 3;         // 0..95
  const int nt  = idx & 7;          // n-tile, fastest
  const int ml  = (idx >> 3) & 3;   // m-local
  const int z   = idx >> 5;         // 0..2
  const int mt  = g * 4 + ml;       // m-tile 0..31
  const u16* Bt = Wt + (size_t)z * HIDN * HIDN;
  const int tid = threadIdx.x;
  const int lane = tid & 63, wave = tid >> 6;
  const int wr = wave >> 1, wc = wave & 1;     // 2x2 waves, each owns 64x64
  const int lg = lane >> 4, li = lane & 15;
  const int bm0 = mt * BM, bn0 = nt * BN;

  const int srow = lane >> 3;          // 0..7 row within 1KB chunk
  const int scol = (lane & 7) * 8;     // k-col element within row

  f32x4 acc[4][4];
  #pragma unroll
  for (int m = 0; m < 4; ++m)
    #pragma unroll
    for (int n = 0; n < 4; ++n) acc[m][n] = (f32x4){0.f, 0.f, 0.f, 0.f};

  for (int k0 = 0; k0 < HIDN; k0 += BK) {
    __syncthreads();
    #pragma unroll
    for (int c = 0; c < 4; ++c) {
      const int ci = wave * 4 + c;
      const int row = ci * 8 + srow;
      gload16(X  + (size_t)(bm0 + row) * HIDN + k0 + scol, &smem[ci * 512]);
      gload16(Bt + (size_t)(bn0 + row) * HIDN + k0 + scol, &smem[8192 + ci * 512]);
    }
    __syncthreads();
    #pragma unroll
    for (int kk = 0; kk < 2; ++kk) {
      s16x8 af[4], bfr[4];
      #pragma unroll
      for (int m = 0; m < 4; ++m) af[m]  = *(const s16x8*)(&smem[(wr * 64 + m * 16 + li) * 64 + kk * 32 + lg * 8]);
      #pragma unroll
      for (int n = 0; n < 4; ++n) bfr[n] = *(const s16x8*)(&smem[8192 + (wc * 64 + n * 16 + li) * 64 + kk * 32 + lg * 8]);
      __builtin_amdgcn_s_setprio(1);
      #pragma unroll
      for (int m = 0; m < 4; ++m)
        #pragma unroll
        for (int n = 0; n < 4; ++n)
          acc[m][n] = __builtin_amdgcn_mfma_f32_16x16x32_bf16(af[m], bfr[n], acc[m][n], 0, 0, 0);
      __builtin_amdgcn_s_setprio(0);
    }
  }

  if (z < 2) {
    u16* dst = (z == 0) ? Qb : Kb;
    #pragma unroll
    for (int m = 0; m < 4; ++m) {
      #pragma unroll
      for (int r = 0; r < 4; ++r) {
        int t = bm0 + wr * 64 + m * 16 + lg * 4 + r;   // global token row
        int b = t >> 11, s = t & (HS - 1);
        #pragma unroll
        for (int n = 0; n < 2; ++n) {                  // rope pairs: frag n with frag n+2
          int c1 = bn0 + wc * 64 + n * 16 + li;        // col for d1 < 32
          float v1 = acc[m][n][r]     + info[(size_t)t * HIDN + c1];
          float v2 = acc[m][n + 2][r] + info[(size_t)t * HIDN + c1 + 32];
          int j = n * 16 + li;                          // freq index 0..31
          float invf = exp2f(-0.41524101186092030f * (float)j);  // 10000^(-j/32)
          float ang = (float)s * invf;
          float sn, cs;
          __sincosf(ang, &sn, &cs);
          float o1 = v1 * cs - v2 * sn;
          float o2 = v2 * cs + v1 * sn;
          if (z == 0) { o1 *= 0.18033688011f; o2 *= 0.18033688011f; } // 1/8 * log2(e)
          int h = c1 >> 6, d1 = c1 & 63;
          size_t base = ((size_t)(b * HH + h) * HS + s) * HD;
          dst[base + d1]      = f2bf(o1);
          dst[base + d1 + 32] = f2bf(o2);
        }
      }
    }
  } else {
    // V: transpose 128x128 block via LDS, then coalesced 16B stores to [B][H][D][S]
    __syncthreads();
    #pragma unroll
    for (int m = 0; m < 4; ++m)
      #pragma unroll
      for (int n = 0; n < 4; ++n)
        #pragma unroll
        for (int r = 0; r < 4; ++r) {
          int cl = wc * 64 + n * 16 + li;
          int ml2 = wr * 64 + m * 16 + lg * 4 + r;
          smem[cl * 136 + ml2] = f2bf(acc[m][n][r]);
        }
    __syncthreads();
    const int b = bm0 >> 11, s0 = bm0 & (HS - 1);
    #pragma unroll
    for (int p = 0; p < 8; ++p) {
      int id = tid + p * 256;
      int cl = id >> 4, m8 = (id & 15) * 8;
      int c = bn0 + cl;
      int h = c >> 6, d = c & 63;
      s16x8 v = *(const s16x8*)(&smem[cl * 136 + m8]);
      *(s16x8*)(&Vt[((size_t)(b * HH + h) * HD + d) * HS + s0 + m8]) = v;
    }
  }
}

// ---------------- K2: causal flash attention (2 q-sets/wave, paired tiles) --
// grid 256 (1/CU, equal work): bh = bidx&31, p = bidx>>5. Block runs q-tile
// 15-p then p (128 q-rows each) -> every block = 34 kv-tiles total.
// Per wave: set A rows q0+w*16+li, set B rows +64. One staged K/V tile serves
// BOTH sets (staging+barriers per work halved); SM_A interleaves with QK_B,
// SM_B with PV_A (intra-wave ILP). No-max softmax (exp2 domain, P=exp2(S-8)).
__global__ __launch_bounds__(256) void k_attn(const u16* __restrict__ Qb, const u16* __restrict__ Kb,
                                              const u16* __restrict__ Vt, u16* __restrict__ attnOut) {
  __shared__ u16 Ks[2][64 * LDK];
  __shared__ u16 Vs[2][64 * LDK];      // V^T tile: [d][key]
  __shared__ u16 Ps[4][2][16 * LDK];   // per-wave, per-set P tile: [qrow][key]
  const int bidx = blockIdx.x;
  const int bh = bidx & 31;
  const int p  = bidx >> 5;            // 0..7

  const u16* Qh = Qb + (size_t)bh * HS * HD;
  const u16* Kh = Kb + (size_t)bh * HS * HD;
  const u16* Vh = Vt + (size_t)bh * HD * HS;
  const int tid = threadIdx.x;
  const int lane = tid & 63, w = tid >> 6;
  const int lg = lane >> 4, li = lane & 15;
  const int b = bh >> 4, h = bh & 15;

  const int row16 = tid >> 3;        // 0..31 (pass 2: +32)
  const int col8  = (tid & 7) * 8;   // 0..56

  #pragma unroll
  for (int ph = 0; ph < 2; ++ph) {
    const int j  = ph ? p : 15 - p;
    const int q0 = j * 128;
    const int ntile = 2 * j + 2;

    // Q fragments for both sets (Q pre-scaled by 0.125*log2e)
    s16x8 qfA[2], qfB[2];
    #pragma unroll
    for (int kk = 0; kk < 2; ++kk) {
      qfA[kk] = *(const s16x8*)(Qh + (size_t)(q0 + w * 16 + li) * HD + kk * 32 + lg * 8);
      qfB[kk] = *(const s16x8*)(Qh + (size_t)(q0 + 64 + w * 16 + li) * HD + kk * 32 + lg * 8);
    }

    f32x4 oA[4], oB[4];
    #pragma unroll
    for (int n = 0; n < 4; ++n) { oA[n] = (f32x4){0.f,0.f,0.f,0.f}; oB[n] = (f32x4){0.f,0.f,0.f,0.f}; }
    float lA = 0.f, lB = 0.f;

    // prologue: stage tile 0 into buf 0 (barrier first: phase-0 LDS may be live)
    {
      uint4 ka = *(const uint4*)(Kh + (size_t)row16 * HD + col8);
      uint4 kb = *(const uint4*)(Kh + (size_t)(row16 + 32) * HD + col8);
      uint4 va = *(const uint4*)(Vh + (size_t)row16 * HS + col8);
      uint4 vb = *(const uint4*)(Vh + (size_t)(row16 + 32) * HS + col8);
      __syncthreads();
      *(uint4*)(&Ks[0][row16 * LDK + col8])        = ka;
      *(uint4*)(&Ks[0][(row16 + 32) * LDK + col8]) = kb;
      *(uint4*)(&Vs[0][row16 * LDK + col8])        = va;
      *(uint4*)(&Vs[0][(row16 + 32) * LDK + col8]) = vb;
    }
    __syncthreads();

    for (int t = 0; t < ntile; ++t) {
      const int cur = t & 1;
      const bool more = (t + 1 < ntile);
      const bool doA  = (t <= 2 * j);    // last tile: keys all > set-A rows
      uint4 rKa, rKb, rVa, rVb;
      if (more) {                        // issue next-tile loads early
        const int kv1 = (t + 1) * 64;
        rKa = *(const uint4*)(Kh + (size_t)(kv1 + row16) * HD + col8);
        rKb = *(const uint4*)(Kh + (size_t)(kv1 + row16 + 32) * HD + col8);
        rVa = *(const uint4*)(Vh + (size_t)row16 * HS + kv1 + col8);
        rVb = *(const uint4*)(Vh + (size_t)(row16 + 32) * HS + kv1 + col8);
      }

      // S^T = K @ Q^T for both sets : lane li owns the q-row, keys n*16+lg*4+r
      f32x4 scA[4], scB[4];
      #pragma unroll
      for (int n = 0; n < 4; ++n) { scA[n] = (f32x4){0.f,0.f,0.f,0.f}; scB[n] = (f32x4){0.f,0.f,0.f,0.f}; }
      __builtin_amdgcn_s_setprio(1);
      if (doA) {
        #pragma unroll
        for (int kk = 0; kk < 2; ++kk)
          #pragma unroll
          for (int n = 0; n < 4; ++n) {
            s16x8 kfr = *(const s16x8*)(&Ks[cur][(n * 16 + li) * LDK + kk * 32 + lg * 8]);
            scA[n] = __builtin_amdgcn_mfma_f32_16x16x32_bf16(kfr, qfA[kk], scA[n], 0, 0, 0);
          }
      }
      #pragma unroll
      for (int kk = 0; kk < 2; ++kk)
        #pragma unroll
        for (int n = 0; n < 4; ++n) {
          s16x8 kfr = *(const s16x8*)(&Ks[cur][(n * 16 + li) * LDK + kk * 32 + lg * 8]);
          scB[n] = __builtin_amdgcn_mfma_f32_16x16x32_bf16(kfr, qfB[kk], scB[n], 0, 0, 0);
        }
      __builtin_amdgcn_s_setprio(0);

      const int qrel = w * 16 + li;      // row rel. to its set's 64-row window
      if (t == 2 * j) {                  // diagonal for set A
        #pragma unroll
        for (int n = 0; n < 4; ++n)
          #pragma unroll
          for (int r = 0; r < 4; ++r)
            if (n * 16 + lg * 4 + r > qrel) scA[n][r] = -1e9f;
      }
      if (t == 2 * j + 1) {              // diagonal for set B
        #pragma unroll
        for (int n = 0; n < 4; ++n)
          #pragma unroll
          for (int r = 0; r < 4; ++r)
            if (n * 16 + lg * 4 + r > qrel) scB[n][r] = -1e9f;
      }

      // SM_A (interleaves with QK_B MFMAs above per scheduler)
      if (doA) {
        float psum = 0.f;
        #pragma unroll
        for (int n = 0; n < 4; ++n) {
          float p0 = exp2f(scA[n][0] - 8.0f);
          float p1 = exp2f(scA[n][1] - 8.0f);
          float p2 = exp2f(scA[n][2] - 8.0f);
          float p3 = exp2f(scA[n][3] - 8.0f);
          psum += (p0 + p1) + (p2 + p3);
          unsigned a0 = __float_as_uint(p0) + 0x8000u;
          unsigned a1 = __float_as_uint(p1) + 0x8000u;
          unsigned a2 = __float_as_uint(p2) + 0x8000u;
          unsigned a3 = __float_as_uint(p3) + 0x8000u;
          uint2 wv;
          wv.x = __builtin_amdgcn_perm(a1, a0, 0x07060302u);
          wv.y = __builtin_amdgcn_perm(a3, a2, 0x07060302u);
          *(uint2*)(&Ps[w][0][li * LDK + n * 16 + lg * 4]) = wv;
        }
        psum += __shfl_xor(psum, 16);
        psum += __shfl_xor(psum, 32);
        lA += psum;

        // PV_A
        __builtin_amdgcn_s_setprio(1);
        #pragma unroll
        for (int kk = 0; kk < 2; ++kk) {
          s16x8 pf = *(const s16x8*)(&Ps[w][0][li * LDK + kk * 32 + lg * 8]);
          #pragma unroll
          for (int n = 0; n < 4; ++n) {
            s16x8 vf = *(const s16x8*)(&Vs[cur][(n * 16 + li) * LDK + kk * 32 + lg * 8]);
            oA[n] = __builtin_amdgcn_mfma_f32_16x16x32_bf16(pf, vf, oA[n], 0, 0, 0);
          }
        }
        __builtin_amdgcn_s_setprio(0);
      }

      // SM_B (interleaves with PV_A MFMAs)
      {
        float psum = 0.f;
        #pragma unroll
        for (int n = 0; n < 4; ++n) {
          float p0 = exp2f(scB[n][0] - 8.0f);
          float p1 = exp2f(scB[n][1] - 8.0f);
          float p2 = exp2f(scB[n][2] - 8.0f);
          float p3 = exp2f(scB[n][3] - 8.0f);
          psum += (p0 + p1) + (p2 + p3);
          unsigned a0 = __float_as_uint(p0) + 0x8000u;
          unsigned a1 = __float_as_uint(p1) + 0x8000u;
          unsigned a2 = __float_as_uint(p2) + 0x8000u;
          unsigned a3 = __float_as_uint(p3) + 0x8000u;
          uint2 wv;
          wv.x = __builtin_amdgcn_perm(a1, a0, 0x07060302u);
          wv.y = __builtin_amdgcn_perm(a3, a2, 0x07060302u);
          *(uint2*)(&Ps[w][1][li * LDK + n * 16 + lg * 4]) = wv;
        }
        psum += __shfl_xor(psum, 16);
        psum += __shfl_xor(psum, 32);
        lB += psum;

        // PV_B
        __builtin_amdgcn_s_setprio(1);
        #pragma unroll
        for (int kk = 0; kk < 2; ++kk) {
          s16x8 pf = *(const s16x8*)(&Ps[w][1][li * LDK + kk * 32 + lg * 8]);
          #pragma unroll
          for (int n = 0; n < 4; ++n) {
            s16x8 vf = *(const s16x8*)(&Vs[cur][(n * 16 + li) * LDK + kk * 32 + lg * 8]);
            oB[n] = __builtin_amdgcn_mfma_f32_16x16x32_bf16(pf, vf, oB[n], 0, 0, 0);
          }
        }
        __builtin_amdgcn_s_setprio(0);
      }

      if (more) {                        // write next tile into other buffer
        *(uint4*)(&Ks[cur ^ 1][row16 * LDK + col8])        = rKa;
        *(uint4*)(&Ks[cur ^ 1][(row16 + 32) * LDK + col8]) = rKb;
        *(uint4*)(&Vs[cur ^ 1][row16 * LDK + col8])        = rVa;
        *(uint4*)(&Vs[cur ^ 1][(row16 + 32) * LDK + col8]) = rVb;
        __syncthreads();
      }
    }

    // epilogue both sets: o row = q(lg*4+r), col = d(n*16+li)
    float linvA = 1.0f / lA, linvB = 1.0f / lB;
    float lqA[4], lqB[4];
    #pragma unroll
    for (int r = 0; r < 4; ++r) { lqA[r] = __shfl(linvA, lg * 4 + r); lqB[r] = __shfl(linvB, lg * 4 + r); }
    #pragma unroll
    for (int n = 0; n < 4; ++n)
      #pragma unroll
      for (int r = 0; r < 4; ++r) {
        int srowA = q0 + w * 16 + lg * 4 + r;
        int srowB = srowA + 64;
        attnOut[(size_t)(b * HS + srowA) * HIDN + h * 64 + n * 16 + li] = f2bf(oA[n][r] * lqA[r]);
        attnOut[(size_t)(b * HS + srowB) * HIDN + h * 64 + n * 16 + li] = f2bf(oB[n][r] * lqB[r]);
      }
  }
}

// ---------------- K3: output GEMM attn @ Wo -> fp32 d_out -------------------
// XCD-aware 1-D grid (256 blocks): XCD g owns m-tiles 4g..4g+3; n fastest.
__global__ __launch_bounds__(256) void k_out(const u16* __restrict__ A, const u16* __restrict__ Bt,
                                             float* __restrict__ out) {
  __shared__ __align__(16) u16 As[BM * 64];
  __shared__ __align__(16) u16 Bs[BN * 64];
  const int bid = blockIdx.x;
  const int g   = bid & 7;
  const int idx = bid >> 3;         // 0..31
  const int nt  = idx & 7;
  const int ml  = idx >> 3;         // 0..3
  const int mt  = g * 4 + ml;
  const int tid = threadIdx.x;
  const int lane = tid & 63, wave = tid >> 6;
  const int wr = wave >> 1, wc = wave & 1;
  const int lg = lane >> 4, li = lane & 15;
  const int bm0 = mt * BM, bn0 = nt * BN;

  const int srow = lane >> 3;
  const int scol = (lane & 7) * 8;

  f32x4 acc[4][4];
  #pragma unroll
  for (int m = 0; m < 4; ++m)
    #pragma unroll
    for (int n = 0; n < 4; ++n) acc[m][n] = (f32x4){0.f, 0.f, 0.f, 0.f};

  for (int k0 = 0; k0 < HIDN; k0 += BK) {
    __syncthreads();
    #pragma unroll
    for (int c = 0; c < 4; ++c) {
      const int ci = wave * 4 + c;
      const int row = ci * 8 + srow;
      gload16(A  + (size_t)(bm0 + row) * HIDN + k0 + scol, &As[ci * 512]);
      gload16(Bt + (size_t)(bn0 + row) * HIDN + k0 + scol, &Bs[ci * 512]);
    }
    __syncthreads();
    #pragma unroll
    for (int kk = 0; kk < 2; ++kk) {
      s16x8 af[4], bfr[4];
      #pragma unroll
      for (int m = 0; m < 4; ++m) af[m]  = *(const s16x8*)(&As[(wr * 64 + m * 16 + li) * 64 + kk * 32 + lg * 8]);
      #pragma unroll
      for (int n = 0; n < 4; ++n) bfr[n] = *(const s16x8*)(&Bs[(wc * 64 + n * 16 + li) * 64 + kk * 32 + lg * 8]);
      __builtin_amdgcn_s_setprio(1);
      #pragma unroll
      for (int m = 0; m < 4; ++m)
        #pragma unroll
        for (int n = 0; n < 4; ++n)
          acc[m][n] = __builtin_amdgcn_mfma_f32_16x16x32_bf16(af[m], bfr[n], acc[m][n], 0, 0, 0);
      __builtin_amdgcn_s_setprio(0);
    }
  }

  #pragma unroll
  for (int m = 0; m < 4; ++m)
    #pragma unroll
    for (int r = 0; r < 4; ++r) {
      int t = bm0 + wr * 64 + m * 16 + lg * 4 + r;
      #pragma unroll
      for (int n = 0; n < 4; ++n) {
        int c = bn0 + wc * 64 + n * 16 + li;
        out[(size_t)t * HIDN + c] = acc[m][n][r];
      }
    }
}

extern "C" void kernel_launch(void* const* d_in, const int* in_sizes, int n_in,
                              void* d_out, int out_size, void* d_ws, size_t ws_size,
                              hipStream_t stream) {
  const float* hs   = (const float*)d_in[0];
  const float* info = (const float*)d_in[1];
  const float* Wq   = (const float*)d_in[2];
  const float* Wk   = (const float*)d_in[3];
  const float* Wv   = (const float*)d_in[4];
  const float* Wo   = (const float*)d_in[5];
  float* out = (float*)d_out;

  char* ws = (char*)d_ws;
  u16* Xbf  = (u16*)(ws);                         // 8 MB, reused as attn buffer after K1
  u16* Wt   = (u16*)(ws + ((size_t)8  << 20));    // 8 MB: Wq^T,Wk^T,Wv^T,Wo^T bf16
  u16* Qb   = (u16*)(ws + ((size_t)16 << 20));    // 8 MB [B][H][S][D]
  u16* Kb   = (u16*)(ws + ((size_t)24 << 20));    // 8 MB [B][H][S][D]
  u16* Vt   = (u16*)(ws + ((size_t)32 << 20));    // 8 MB [B][H][D][S]
  u16* attn = Xbf;                                 // [4096][1024] bf16

  k_cvt<<<(MROWS * HIDN / 4 + 255) / 256, 256, 0, stream>>>(hs, Xbf, MROWS * HIDN);
  k_transpose<<<dim3(16, 16, 4), 256, 0, stream>>>(Wq, Wk, Wv, Wo, Wt);
  k_qkv<<<dim3(768), 256, 0, stream>>>(Xbf, Wt, info, Qb, Kb, Vt);
  k_attn<<<dim3(256), 256, 0, stream>>>(Qb, Kb, Vt, attn);
  k_out<<<dim3(256), 256, 0, stream>>>(attn, Wt + (size_t)3 * HIDN * HIDN, out);
}

// Round 11
// 112.699 us; speedup vs baseline: 1.2306x; 1.2306x over previous
//
#include <hip/hip_runtime.h>
#include <hip/hip_bf16.h>

// Problem constants
#define HB 2
#define HS 2048
#define HH 16
#define HD 64
#define HIDN 1024
#define MROWS 4096   // B*S

typedef __attribute__((ext_vector_type(8))) short s16x8;   // 8 bf16 (4 VGPRs)
typedef __attribute__((ext_vector_type(4))) float f32x4;   // MFMA accumulator
typedef unsigned short u16;

__device__ inline u16 f2bf(float f) {
  union { __hip_bfloat16 h; u16 u; } cvt;
  cvt.h = __float2bfloat16(f);
  return cvt.u;
}

// async global->LDS DMA, 16B per lane. lds base must be wave-uniform;
// lane i lands at base + i*16B. global addr is per-lane.
__device__ __forceinline__ void gload16(const u16* g, u16* l) {
  __builtin_amdgcn_global_load_lds((const __attribute__((address_space(1))) void*)g,
                                   (__attribute__((address_space(3))) void*)l, 16, 0, 0);
}

// ---------------- K0: fused prep — weight transpose (bid<1024) + X convert --
// transpose: fp32 W[K][C] -> bf16 W^T[C][K] for Wq,Wk,Wv,Wo
// convert:   fp32 hidden -> bf16 (4 elems/thread)
__global__ __launch_bounds__(256) void k_prep(const float* __restrict__ hs,
                                              const float* __restrict__ W0, const float* __restrict__ W1,
                                              const float* __restrict__ W2, const float* __restrict__ W3,
                                              u16* __restrict__ Wt, u16* __restrict__ Xbf) {
  const int bid = blockIdx.x;
  if (bid < 1024) {
    const int z = bid >> 8, y = (bid >> 4) & 15, x = bid & 15;
    const float* W = (z == 0) ? W0 : (z == 1) ? W1 : (z == 2) ? W2 : W3;
    u16* O = Wt + (size_t)z * HIDN * HIDN;
    __shared__ float tile[64][65];
    int k0 = y * 64, c0 = x * 64;
    #pragma unroll
    for (int i = 0; i < 16; ++i) {
      int id = threadIdx.x + i * 256;
      int r = id >> 6, c = id & 63;
      tile[r][c] = W[(size_t)(k0 + r) * HIDN + c0 + c];
    }
    __syncthreads();
    #pragma unroll
    for (int i = 0; i < 16; ++i) {
      int id = threadIdx.x + i * 256;
      int r = id >> 6, c = id & 63;
      O[(size_t)(c0 + r) * HIDN + k0 + c] = f2bf(tile[c][r]);
    }
  } else {
    int i = ((bid - 1024) * 256 + threadIdx.x) * 4;
    float4 a = *(const float4*)(hs + i);
    ushort4 r;
    r.x = f2bf(a.x); r.y = f2bf(a.y); r.z = f2bf(a.z); r.w = f2bf(a.w);
    *(ushort4*)(Xbf + i) = r;
  }
}

// ---------------- K1: QKV GEMM + info add + RoPE epilogue -------------------
// XCD-aware 1-D grid (768 blocks): XCD g owns m-tiles 4g..4g+3 (A-panels stay
// L2-resident); n fastest (B-panel 2MB/z L2-resident); z outermost.
#define BM 128
#define BN 128
#define BK 64
#define LDK 72   // padded stride for k_attn LDS tiles (16B-aligned rows)

__global__ __launch_bounds__(256) void k_qkv(const u16* __restrict__ X, const u16* __restrict__ Wt,
                                             const float* __restrict__ info,
                                             u16* __restrict__ Qb, u16* __restrict__ Kb, u16* __restrict__ Vt) {
  __shared__ __align__(16) u16 smem[128 * 136];
  const int bid = blockIdx.x;
  const int g   = bid & 7;          // XCD (bid%8 round-robin)
  const int idx = bid >> 3;         // 0..95
  const int nt  = idx & 7;          // n-tile, fastest
  const int ml  = (idx >> 3) & 3;   // m-local
  const int z   = idx >> 5;         // 0..2
  const int mt  = g * 4 + ml;       // m-tile 0..31
  const u16* Bt = Wt + (size_t)z * HIDN * HIDN;
  const int tid = threadIdx.x;
  const int lane = tid & 63, wave = tid >> 6;
  const int wr = wave >> 1, wc = wave & 1;     // 2x2 waves, each owns 64x64
  const int lg = lane >> 4, li = lane & 15;
  const int bm0 = mt * BM, bn0 = nt * BN;

  const int srow = lane >> 3;          // 0..7 row within 1KB chunk
  const int scol = (lane & 7) * 8;     // k-col element within row

  f32x4 acc[4][4];
  #pragma unroll
  for (int m = 0; m < 4; ++m)
    #pragma unroll
    for (int n = 0; n < 4; ++n) acc[m][n] = (f32x4){0.f, 0.f, 0.f, 0.f};

  for (int k0 = 0; k0 < HIDN; k0 += BK) {
    __syncthreads();
    #pragma unroll
    for (int c = 0; c < 4; ++c) {
      const int ci = wave * 4 + c;
      const int row = ci * 8 + srow;
      gload16(X  + (size_t)(bm0 + row) * HIDN + k0 + scol, &smem[ci * 512]);
      gload16(Bt + (size_t)(bn0 + row) * HIDN + k0 + scol, &smem[8192 + ci * 512]);
    }
    __syncthreads();
    #pragma unroll
    for (int kk = 0; kk < 2; ++kk) {
      s16x8 af[4], bfr[4];
      #pragma unroll
      for (int m = 0; m < 4; ++m) af[m]  = *(const s16x8*)(&smem[(wr * 64 + m * 16 + li) * 64 + kk * 32 + lg * 8]);
      #pragma unroll
      for (int n = 0; n < 4; ++n) bfr[n] = *(const s16x8*)(&smem[8192 + (wc * 64 + n * 16 + li) * 64 + kk * 32 + lg * 8]);
      __builtin_amdgcn_s_setprio(1);
      #pragma unroll
      for (int m = 0; m < 4; ++m)
        #pragma unroll
        for (int n = 0; n < 4; ++n)
          acc[m][n] = __builtin_amdgcn_mfma_f32_16x16x32_bf16(af[m], bfr[n], acc[m][n], 0, 0, 0);
      __builtin_amdgcn_s_setprio(0);
    }
  }

  if (z < 2) {
    u16* dst = (z == 0) ? Qb : Kb;
    #pragma unroll
    for (int m = 0; m < 4; ++m) {
      #pragma unroll
      for (int r = 0; r < 4; ++r) {
        int t = bm0 + wr * 64 + m * 16 + lg * 4 + r;   // global token row
        int b = t >> 11, s = t & (HS - 1);
        #pragma unroll
        for (int n = 0; n < 2; ++n) {                  // rope pairs: frag n with frag n+2
          int c1 = bn0 + wc * 64 + n * 16 + li;        // col for d1 < 32
          float v1 = acc[m][n][r]     + info[(size_t)t * HIDN + c1];
          float v2 = acc[m][n + 2][r] + info[(size_t)t * HIDN + c1 + 32];
          int j = n * 16 + li;                          // freq index 0..31
          float invf = exp2f(-0.41524101186092030f * (float)j);  // 10000^(-j/32)
          float ang = (float)s * invf;
          float sn, cs;
          __sincosf(ang, &sn, &cs);
          float o1 = v1 * cs - v2 * sn;
          float o2 = v2 * cs + v1 * sn;
          if (z == 0) { o1 *= 0.18033688011f; o2 *= 0.18033688011f; } // 1/8 * log2(e)
          int h = c1 >> 6, d1 = c1 & 63;
          size_t base = ((size_t)(b * HH + h) * HS + s) * HD;
          dst[base + d1]      = f2bf(o1);
          dst[base + d1 + 32] = f2bf(o2);
        }
      }
    }
  } else {
    // V: transpose 128x128 block via LDS, then coalesced 16B stores to [B][H][D][S]
    __syncthreads();
    #pragma unroll
    for (int m = 0; m < 4; ++m)
      #pragma unroll
      for (int n = 0; n < 4; ++n)
        #pragma unroll
        for (int r = 0; r < 4; ++r) {
          int cl = wc * 64 + n * 16 + li;
          int ml2 = wr * 64 + m * 16 + lg * 4 + r;
          smem[cl * 136 + ml2] = f2bf(acc[m][n][r]);
        }
    __syncthreads();
    const int b = bm0 >> 11, s0 = bm0 & (HS - 1);
    #pragma unroll
    for (int p = 0; p < 8; ++p) {
      int id = tid + p * 256;
      int cl = id >> 4, m8 = (id & 15) * 8;
      int c = bn0 + cl;
      int h = c >> 6, d = c & 63;
      s16x8 v = *(const s16x8*)(&smem[cl * 136 + m8]);
      *(s16x8*)(&Vt[((size_t)(b * HH + h) * HD + d) * HS + s0 + m8]) = v;
    }
  }
}

// ---------------- K2: causal flash attention (4-wave, dbuf, MFMA row-sum) ---
// grid 1024: bh = bidx&31, j = 31 - (bidx>>5) -> largest-work blocks first,
// rest backfill. Block = 4 waves x 16 q-rows at q0=j*64; ntiles = j+1.
// No-max softmax: P = exp2(S) (S bounded ~6, division cancels scale).
// Row-sum l computed BY THE MATRIX PIPE: ones-column B-frag appended to PV ->
// ol[r] = l for q-row lg*4+r, exactly the epilogue layout (no shuffles at all).
__global__ __launch_bounds__(256, 3) void k_attn(const u16* __restrict__ Qb, const u16* __restrict__ Kb,
                                                 const u16* __restrict__ Vt, u16* __restrict__ attnOut) {
  __shared__ u16 Ks[2][64 * LDK];
  __shared__ u16 Vs[2][64 * LDK];   // V^T tile: [d][key]
  __shared__ u16 Ps[4][16 * LDK];   // per-wave P tile: [qrow][key]
  const int bidx = blockIdx.x;
  const int bh = bidx & 31;
  const int j  = 31 - (bidx >> 5);
  const int q0 = j * 64;
  const int ntiles = j + 1;

  const u16* Qh = Qb + (size_t)bh * HS * HD;
  const u16* Kh = Kb + (size_t)bh * HS * HD;
  const u16* Vh = Vt + (size_t)bh * HD * HS;
  const int tid = threadIdx.x;
  const int lane = tid & 63, w = tid >> 6;
  const int lg = lane >> 4, li = lane & 15;
  const int b = bh >> 4, h = bh & 15;

  const int row16 = tid >> 3;        // 0..31 (pass 2: +32)
  const int col8  = (tid & 7) * 8;   // 0..56

  // Q fragments in registers (Q pre-scaled by 0.125*log2e)
  s16x8 qf[2];
  #pragma unroll
  for (int kk = 0; kk < 2; ++kk)
    qf[kk] = *(const s16x8*)(Qh + (size_t)(q0 + w * 16 + li) * HD + kk * 32 + lg * 8);

  // all-ones bf16 fragment for the l row-sum MFMA
  s16x8 vones;
  #pragma unroll
  for (int e = 0; e < 8; ++e) vones[e] = (short)0x3F80;

  f32x4 o[4];
  #pragma unroll
  for (int n = 0; n < 4; ++n) o[n] = (f32x4){0.f, 0.f, 0.f, 0.f};
  f32x4 ol = (f32x4){0.f, 0.f, 0.f, 0.f};   // ol[r] = running l for q-row lg*4+r

  // prologue: stage tile 0 into buf 0
  {
    uint4 ka = *(const uint4*)(Kh + (size_t)row16 * HD + col8);
    uint4 kb = *(const uint4*)(Kh + (size_t)(row16 + 32) * HD + col8);
    uint4 va = *(const uint4*)(Vh + (size_t)row16 * HS + col8);
    uint4 vb = *(const uint4*)(Vh + (size_t)(row16 + 32) * HS + col8);
    *(uint4*)(&Ks[0][row16 * LDK + col8])        = ka;
    *(uint4*)(&Ks[0][(row16 + 32) * LDK + col8]) = kb;
    *(uint4*)(&Vs[0][row16 * LDK + col8])        = va;
    *(uint4*)(&Vs[0][(row16 + 32) * LDK + col8]) = vb;
  }
  __syncthreads();

  for (int t = 0; t < ntiles; ++t) {
    const int cur = t & 1;
    uint4 rKa, rKb, rVa, rVb;
    const bool more = (t + 1 < ntiles);
    if (more) {                       // issue next-tile loads early (hide latency)
      const int kv1 = (t + 1) * 64;
      rKa = *(const uint4*)(Kh + (size_t)(kv1 + row16) * HD + col8);
      rKb = *(const uint4*)(Kh + (size_t)(kv1 + row16 + 32) * HD + col8);
      rVa = *(const uint4*)(Vh + (size_t)row16 * HS + kv1 + col8);
      rVb = *(const uint4*)(Vh + (size_t)(row16 + 32) * HS + kv1 + col8);
    }

    // S^T = K @ Q^T : lane li owns q-row (q0+w*16+li), keys n*16+lg*4+r
    f32x4 sc[4];
    #pragma unroll
    for (int n = 0; n < 4; ++n) sc[n] = (f32x4){0.f, 0.f, 0.f, 0.f};
    __builtin_amdgcn_s_setprio(1);
    #pragma unroll
    for (int kk = 0; kk < 2; ++kk) {
      #pragma unroll
      for (int n = 0; n < 4; ++n) {
        s16x8 kfr = *(const s16x8*)(&Ks[cur][(n * 16 + li) * LDK + kk * 32 + lg * 8]);
        sc[n] = __builtin_amdgcn_mfma_f32_16x16x32_bf16(kfr, qf[kk], sc[n], 0, 0, 0);
      }
    }
    __builtin_amdgcn_s_setprio(0);

    if (t == ntiles - 1) {            // diagonal tile: mask key > query
      const int qrel = w * 16 + li;
      #pragma unroll
      for (int n = 0; n < 4; ++n)
        #pragma unroll
        for (int r = 0; r < 4; ++r)
          if (n * 16 + lg * 4 + r > qrel) sc[n][r] = -1e9f;
    }

    // no-max softmax: P = exp2(S); pack to bf16 for PV (l comes from MFMA)
    #pragma unroll
    for (int n = 0; n < 4; ++n) {
      float p0 = exp2f(sc[n][0]);
      float p1 = exp2f(sc[n][1]);
      float p2 = exp2f(sc[n][2]);
      float p3 = exp2f(sc[n][3]);
      // fast bf16 pair-pack: +0x8000 round bias, v_perm selects hi16 halves
      unsigned a0 = __float_as_uint(p0) + 0x8000u;
      unsigned a1 = __float_as_uint(p1) + 0x8000u;
      unsigned a2 = __float_as_uint(p2) + 0x8000u;
      unsigned a3 = __float_as_uint(p3) + 0x8000u;
      uint2 wv;
      wv.x = __builtin_amdgcn_perm(a1, a0, 0x07060302u);  // hi16(a1)<<16 | hi16(a0)
      wv.y = __builtin_amdgcn_perm(a3, a2, 0x07060302u);
      *(uint2*)(&Ps[w][li * LDK + n * 16 + lg * 4]) = wv;
    }

    // O += P @ V ; l += P @ 1
    __builtin_amdgcn_s_setprio(1);
    #pragma unroll
    for (int kk = 0; kk < 2; ++kk) {
      s16x8 pf = *(const s16x8*)(&Ps[w][li * LDK + kk * 32 + lg * 8]);
      #pragma unroll
      for (int n = 0; n < 4; ++n) {
        s16x8 vf = *(const s16x8*)(&Vs[cur][(n * 16 + li) * LDK + kk * 32 + lg * 8]);
        o[n] = __builtin_amdgcn_mfma_f32_16x16x32_bf16(pf, vf, o[n], 0, 0, 0);
      }
      ol = __builtin_amdgcn_mfma_f32_16x16x32_bf16(pf, vones, ol, 0, 0, 0);
    }
    __builtin_amdgcn_s_setprio(0);

    if (more) {                       // write next tile into other buffer
      *(uint4*)(&Ks[cur ^ 1][row16 * LDK + col8])        = rKa;
      *(uint4*)(&Ks[cur ^ 1][(row16 + 32) * LDK + col8]) = rKb;
      *(uint4*)(&Vs[cur ^ 1][row16 * LDK + col8])        = rVa;
      *(uint4*)(&Vs[cur ^ 1][(row16 + 32) * LDK + col8]) = rVb;
      __syncthreads();
    }
  }

  // epilogue: attn[b][s][h*64+d] bf16 ; o row = q(lg*4+r), col = d(n*16+li)
  // ol[r] is l for q-row lg*4+r — same layout as o, no cross-lane needed.
  float linvq[4];
  #pragma unroll
  for (int r = 0; r < 4; ++r) linvq[r] = 1.0f / ol[r];
  #pragma unroll
  for (int n = 0; n < 4; ++n)
    #pragma unroll
    for (int r = 0; r < 4; ++r) {
      int srow = q0 + w * 16 + lg * 4 + r;
      attnOut[(size_t)(b * HS + srow) * HIDN + h * 64 + n * 16 + li] = f2bf(o[n][r] * linvq[r]);
    }
}

// ---------------- K3: output GEMM attn @ Wo -> fp32 d_out -------------------
// XCD-aware 1-D grid (256 blocks): XCD g owns m-tiles 4g..4g+3; n fastest.
__global__ __launch_bounds__(256) void k_out(const u16* __restrict__ A, const u16* __restrict__ Bt,
                                             float* __restrict__ out) {
  __shared__ __align__(16) u16 As[BM * 64];
  __shared__ __align__(16) u16 Bs[BN * 64];
  const int bid = blockIdx.x;
  const int g   = bid & 7;
  const int idx = bid >> 3;         // 0..31
  const int nt  = idx & 7;
  const int ml  = idx >> 3;         // 0..3
  const int mt  = g * 4 + ml;
  const int tid = threadIdx.x;
  const int lane = tid & 63, wave = tid >> 6;
  const int wr = wave >> 1, wc = wave & 1;
  const int lg = lane >> 4, li = lane & 15;
  const int bm0 = mt * BM, bn0 = nt * BN;

  const int srow = lane >> 3;
  const int scol = (lane & 7) * 8;

  f32x4 acc[4][4];
  #pragma unroll
  for (int m = 0; m < 4; ++m)
    #pragma unroll
    for (int n = 0; n < 4; ++n) acc[m][n] = (f32x4){0.f, 0.f, 0.f, 0.f};

  for (int k0 = 0; k0 < HIDN; k0 += BK) {
    __syncthreads();
    #pragma unroll
    for (int c = 0; c < 4; ++c) {
      const int ci = wave * 4 + c;
      const int row = ci * 8 + srow;
      gload16(A  + (size_t)(bm0 + row) * HIDN + k0 + scol, &As[ci * 512]);
      gload16(Bt + (size_t)(bn0 + row) * HIDN + k0 + scol, &Bs[ci * 512]);
    }
    __syncthreads();
    #pragma unroll
    for (int kk = 0; kk < 2; ++kk) {
      s16x8 af[4], bfr[4];
      #pragma unroll
      for (int m = 0; m < 4; ++m) af[m]  = *(const s16x8*)(&As[(wr * 64 + m * 16 + li) * 64 + kk * 32 + lg * 8]);
      #pragma unroll
      for (int n = 0; n < 4; ++n) bfr[n] = *(const s16x8*)(&Bs[(wc * 64 + n * 16 + li) * 64 + kk * 32 + lg * 8]);
      __builtin_amdgcn_s_setprio(1);
      #pragma unroll
      for (int m = 0; m < 4; ++m)
        #pragma unroll
        for (int n = 0; n < 4; ++n)
          acc[m][n] = __builtin_amdgcn_mfma_f32_16x16x32_bf16(af[m], bfr[n], acc[m][n], 0, 0, 0);
      __builtin_amdgcn_s_setprio(0);
    }
  }

  #pragma unroll
  for (int m = 0; m < 4; ++m)
    #pragma unroll
    for (int r = 0; r < 4; ++r) {
      int t = bm0 + wr * 64 + m * 16 + lg * 4 + r;
      #pragma unroll
      for (int n = 0; n < 4; ++n) {
        int c = bn0 + wc * 64 + n * 16 + li;
        out[(size_t)t * HIDN + c] = acc[m][n][r];
      }
    }
}

extern "C" void kernel_launch(void* const* d_in, const int* in_sizes, int n_in,
                              void* d_out, int out_size, void* d_ws, size_t ws_size,
                              hipStream_t stream) {
  const float* hs   = (const float*)d_in[0];
  const float* info = (const float*)d_in[1];
  const float* Wq   = (const float*)d_in[2];
  const float* Wk   = (const float*)d_in[3];
  const float* Wv   = (const float*)d_in[4];
  const float* Wo   = (const float*)d_in[5];
  float* out = (float*)d_out;

  char* ws = (char*)d_ws;
  u16* Xbf  = (u16*)(ws);                         // 8 MB, reused as attn buffer after K1
  u16* Wt   = (u16*)(ws + ((size_t)8  << 20));    // 8 MB: Wq^T,Wk^T,Wv^T,Wo^T bf16
  u16* Qb   = (u16*)(ws + ((size_t)16 << 20));    // 8 MB [B][H][S][D]
  u16* Kb   = (u16*)(ws + ((size_t)24 << 20));    // 8 MB [B][H][S][D]
  u16* Vt   = (u16*)(ws + ((size_t)32 << 20));    // 8 MB [B][H][D][S]
  u16* attn = Xbf;                                 // [4096][1024] bf16

  k_prep<<<dim3(1024 + MROWS * HIDN / 1024), 256, 0, stream>>>(hs, Wq, Wk, Wv, Wo, Wt, Xbf);
  k_qkv<<<dim3(768), 256, 0, stream>>>(Xbf, Wt, info, Qb, Kb, Vt);
  k_attn<<<dim3(1024), 256, 0, stream>>>(Qb, Kb, Vt, attn);
  k_out<<<dim3(256), 256, 0, stream>>>(attn, Wt + (size_t)3 * HIDN * HIDN, out);
}

// Round 12
// 112.598 us; speedup vs baseline: 1.2317x; 1.0009x over previous
//
#include <hip/hip_runtime.h>
#include <hip/hip_bf16.h>

// Problem constants
#define HB 2
#define HS 2048
#define HH 16
#define HD 64
#define HIDN 1024
#define MROWS 4096   // B*S

typedef __attribute__((ext_vector_type(8))) short s16x8;   // 8 bf16 (4 VGPRs)
typedef __attribute__((ext_vector_type(4))) float f32x4;   // MFMA accumulator
typedef unsigned short u16;

__device__ inline u16 f2bf(float f) {
  union { __hip_bfloat16 h; u16 u; } cvt;
  cvt.h = __float2bfloat16(f);
  return cvt.u;
}

// async global->LDS DMA, 16B per lane. lds base must be wave-uniform;
// lane i lands at base + i*16B. global addr is per-lane.
__device__ __forceinline__ void gload16(const u16* g, u16* l) {
  __builtin_amdgcn_global_load_lds((const __attribute__((address_space(1))) void*)g,
                                   (__attribute__((address_space(3))) void*)l, 16, 0, 0);
}

// ---------------- K0: fused prep — weight transpose (bid<1024) + X convert --
__global__ __launch_bounds__(256) void k_prep(const float* __restrict__ hs,
                                              const float* __restrict__ W0, const float* __restrict__ W1,
                                              const float* __restrict__ W2, const float* __restrict__ W3,
                                              u16* __restrict__ Wt, u16* __restrict__ Xbf) {
  const int bid = blockIdx.x;
  if (bid < 1024) {
    const int z = bid >> 8, y = (bid >> 4) & 15, x = bid & 15;
    const float* W = (z == 0) ? W0 : (z == 1) ? W1 : (z == 2) ? W2 : W3;
    u16* O = Wt + (size_t)z * HIDN * HIDN;
    __shared__ float tile[64][65];
    int k0 = y * 64, c0 = x * 64;
    #pragma unroll
    for (int i = 0; i < 16; ++i) {
      int id = threadIdx.x + i * 256;
      int r = id >> 6, c = id & 63;
      tile[r][c] = W[(size_t)(k0 + r) * HIDN + c0 + c];
    }
    __syncthreads();
    #pragma unroll
    for (int i = 0; i < 16; ++i) {
      int id = threadIdx.x + i * 256;
      int r = id >> 6, c = id & 63;
      O[(size_t)(c0 + r) * HIDN + k0 + c] = f2bf(tile[c][r]);
    }
  } else {
    int i = ((bid - 1024) * 256 + threadIdx.x) * 4;
    float4 a = *(const float4*)(hs + i);
    ushort4 r;
    r.x = f2bf(a.x); r.y = f2bf(a.y); r.z = f2bf(a.z); r.w = f2bf(a.w);
    *(ushort4*)(Xbf + i) = r;
  }
}

// ---------------- K1: QKV GEMM + info add + RoPE epilogue -------------------
// XCD-aware 1-D grid (768 blocks): XCD g owns m-tiles 4g..4g+3 (A-panels stay
// L2-resident); n fastest (B-panel 2MB/z L2-resident); z outermost.
#define BM 128
#define BN 128
#define BK 64
#define LDK 72   // padded stride for k_attn LDS tiles (16B-aligned rows)

__global__ __launch_bounds__(256) void k_qkv(const u16* __restrict__ X, const u16* __restrict__ Wt,
                                             const float* __restrict__ info,
                                             u16* __restrict__ Qb, u16* __restrict__ Kb, u16* __restrict__ Vt) {
  __shared__ __align__(16) u16 smem[128 * 136];
  const int bid = blockIdx.x;
  const int g   = bid & 7;          // XCD (bid%8 round-robin)
  const int idx = bid >> 3;         // 0..95
  const int nt  = idx & 7;          // n-tile, fastest
  const int ml  = (idx >> 3) & 3;   // m-local
  const int z   = idx >> 5;         // 0..2
  const int mt  = g * 4 + ml;       // m-tile 0..31
  const u16* Bt = Wt + (size_t)z * HIDN * HIDN;
  const int tid = threadIdx.x;
  const int lane = tid & 63, wave = tid >> 6;
  const int wr = wave >> 1, wc = wave & 1;     // 2x2 waves, each owns 64x64
  const int lg = lane >> 4, li = lane & 15;
  const int bm0 = mt * BM, bn0 = nt * BN;

  const int srow = lane >> 3;          // 0..7 row within 1KB chunk
  const int scol = (lane & 7) * 8;     // k-col element within row

  f32x4 acc[4][4];
  #pragma unroll
  for (int m = 0; m < 4; ++m)
    #pragma unroll
    for (int n = 0; n < 4; ++n) acc[m][n] = (f32x4){0.f, 0.f, 0.f, 0.f};

  for (int k0 = 0; k0 < HIDN; k0 += BK) {
    __syncthreads();
    #pragma unroll
    for (int c = 0; c < 4; ++c) {
      const int ci = wave * 4 + c;
      const int row = ci * 8 + srow;
      gload16(X  + (size_t)(bm0 + row) * HIDN + k0 + scol, &smem[ci * 512]);
      gload16(Bt + (size_t)(bn0 + row) * HIDN + k0 + scol, &smem[8192 + ci * 512]);
    }
    __syncthreads();
    #pragma unroll
    for (int kk = 0; kk < 2; ++kk) {
      s16x8 af[4], bfr[4];
      #pragma unroll
      for (int m = 0; m < 4; ++m) af[m]  = *(const s16x8*)(&smem[(wr * 64 + m * 16 + li) * 64 + kk * 32 + lg * 8]);
      #pragma unroll
      for (int n = 0; n < 4; ++n) bfr[n] = *(const s16x8*)(&smem[8192 + (wc * 64 + n * 16 + li) * 64 + kk * 32 + lg * 8]);
      __builtin_amdgcn_s_setprio(1);
      #pragma unroll
      for (int m = 0; m < 4; ++m)
        #pragma unroll
        for (int n = 0; n < 4; ++n)
          acc[m][n] = __builtin_amdgcn_mfma_f32_16x16x32_bf16(af[m], bfr[n], acc[m][n], 0, 0, 0);
      __builtin_amdgcn_s_setprio(0);
    }
  }

  if (z < 2) {
    u16* dst = (z == 0) ? Qb : Kb;
    // RoPE trig diet: inv-freq (in REVOLUTIONS) depends only on this thread's
    // two j values -> hoist (2 exp2f instead of 32). Angle via revolutions-
    // domain sincos: v_sin/v_cos compute sin(2*pi*x); reduce with fract.
    float invr[2];
    #pragma unroll
    for (int n = 0; n < 2; ++n)
      invr[n] = exp2f(-0.41524101186092030f * (float)(n * 16 + li)) * 0.15915494309189535f;
    #pragma unroll
    for (int m = 0; m < 4; ++m) {
      #pragma unroll
      for (int r = 0; r < 4; ++r) {
        int t = bm0 + wr * 64 + m * 16 + lg * 4 + r;   // global token row
        int b = t >> 11, s = t & (HS - 1);
        #pragma unroll
        for (int n = 0; n < 2; ++n) {                  // rope pairs: frag n with frag n+2
          int c1 = bn0 + wc * 64 + n * 16 + li;        // col for d1 < 32
          float v1 = acc[m][n][r]     + info[(size_t)t * HIDN + c1];
          float v2 = acc[m][n + 2][r] + info[(size_t)t * HIDN + c1 + 32];
          float rev = (float)s * invr[n];
          rev -= floorf(rev);                          // -> [0,1) revolutions
          float sn = __builtin_amdgcn_sinf(rev);       // sin(2*pi*rev)
          float cs = __builtin_amdgcn_cosf(rev);
          float o1 = v1 * cs - v2 * sn;
          float o2 = v2 * cs + v1 * sn;
          if (z == 0) { o1 *= 0.18033688011f; o2 *= 0.18033688011f; } // 1/8 * log2(e)
          int h = c1 >> 6, d1 = c1 & 63;
          size_t base = ((size_t)(b * HH + h) * HS + s) * HD;
          dst[base + d1]      = f2bf(o1);
          dst[base + d1 + 32] = f2bf(o2);
        }
      }
    }
  } else {
    // V: transpose 128x128 block via LDS, then coalesced 16B stores to [B][H][D][S]
    __syncthreads();
    #pragma unroll
    for (int m = 0; m < 4; ++m)
      #pragma unroll
      for (int n = 0; n < 4; ++n)
        #pragma unroll
        for (int r = 0; r < 4; ++r) {
          int cl = wc * 64 + n * 16 + li;
          int ml2 = wr * 64 + m * 16 + lg * 4 + r;
          smem[cl * 136 + ml2] = f2bf(acc[m][n][r]);
        }
    __syncthreads();
    const int b = bm0 >> 11, s0 = bm0 & (HS - 1);
    #pragma unroll
    for (int p = 0; p < 8; ++p) {
      int id = tid + p * 256;
      int cl = id >> 4, m8 = (id & 15) * 8;
      int c = bn0 + cl;
      int h = c >> 6, d = c & 63;
      s16x8 v = *(const s16x8*)(&smem[cl * 136 + m8]);
      *(s16x8*)(&Vt[((size_t)(b * HH + h) * HD + d) * HS + s0 + m8]) = v;
    }
  }
}

// ---------------- K2: causal flash attention (4-wave, dbuf, MFMA row-sum) ---
// grid 1024: bh = bidx&31, j = 31 - (bidx>>5) -> largest-work blocks first,
// rest backfill. Block = 4 waves x 16 q-rows at q0=j*64; ntiles = j+1.
// No-max softmax: P = exp2(S) (S bounded ~6, division cancels scale).
// Row-sum l computed BY THE MATRIX PIPE: ones-column B-frag appended to PV ->
// ol[r] = l for q-row lg*4+r, exactly the epilogue layout (no shuffles at all).
__global__ __launch_bounds__(256, 3) void k_attn(const u16* __restrict__ Qb, const u16* __restrict__ Kb,
                                                 const u16* __restrict__ Vt, u16* __restrict__ attnOut) {
  __shared__ u16 Ks[2][64 * LDK];
  __shared__ u16 Vs[2][64 * LDK];   // V^T tile: [d][key]
  __shared__ u16 Ps[4][16 * LDK];   // per-wave P tile: [qrow][key]
  const int bidx = blockIdx.x;
  const int bh = bidx & 31;
  const int j  = 31 - (bidx >> 5);
  const int q0 = j * 64;
  const int ntiles = j + 1;

  const u16* Qh = Qb + (size_t)bh * HS * HD;
  const u16* Kh = Kb + (size_t)bh * HS * HD;
  const u16* Vh = Vt + (size_t)bh * HD * HS;
  const int tid = threadIdx.x;
  const int lane = tid & 63, w = tid >> 6;
  const int lg = lane >> 4, li = lane & 15;
  const int b = bh >> 4, h = bh & 15;

  const int row16 = tid >> 3;        // 0..31 (pass 2: +32)
  const int col8  = (tid & 7) * 8;   // 0..56

  // Q fragments in registers (Q pre-scaled by 0.125*log2e)
  s16x8 qf[2];
  #pragma unroll
  for (int kk = 0; kk < 2; ++kk)
    qf[kk] = *(const s16x8*)(Qh + (size_t)(q0 + w * 16 + li) * HD + kk * 32 + lg * 8);

  // all-ones bf16 fragment for the l row-sum MFMA
  s16x8 vones;
  #pragma unroll
  for (int e = 0; e < 8; ++e) vones[e] = (short)0x3F80;

  f32x4 o[4];
  #pragma unroll
  for (int n = 0; n < 4; ++n) o[n] = (f32x4){0.f, 0.f, 0.f, 0.f};
  f32x4 ol = (f32x4){0.f, 0.f, 0.f, 0.f};   // ol[r] = running l for q-row lg*4+r

  // prologue: stage tile 0 into buf 0
  {
    uint4 ka = *(const uint4*)(Kh + (size_t)row16 * HD + col8);
    uint4 kb = *(const uint4*)(Kh + (size_t)(row16 + 32) * HD + col8);
    uint4 va = *(const uint4*)(Vh + (size_t)row16 * HS + col8);
    uint4 vb = *(const uint4*)(Vh + (size_t)(row16 + 32) * HS + col8);
    *(uint4*)(&Ks[0][row16 * LDK + col8])        = ka;
    *(uint4*)(&Ks[0][(row16 + 32) * LDK + col8]) = kb;
    *(uint4*)(&Vs[0][row16 * LDK + col8])        = va;
    *(uint4*)(&Vs[0][(row16 + 32) * LDK + col8]) = vb;
  }
  __syncthreads();

  for (int t = 0; t < ntiles; ++t) {
    const int cur = t & 1;
    uint4 rKa, rKb, rVa, rVb;
    const bool more = (t + 1 < ntiles);
    if (more) {                       // issue next-tile loads early (hide latency)
      const int kv1 = (t + 1) * 64;
      rKa = *(const uint4*)(Kh + (size_t)(kv1 + row16) * HD + col8);
      rKb = *(const uint4*)(Kh + (size_t)(kv1 + row16 + 32) * HD + col8);
      rVa = *(const uint4*)(Vh + (size_t)row16 * HS + kv1 + col8);
      rVb = *(const uint4*)(Vh + (size_t)(row16 + 32) * HS + kv1 + col8);
    }

    // S^T = K @ Q^T : lane li owns q-row (q0+w*16+li), keys n*16+lg*4+r
    f32x4 sc[4];
    #pragma unroll
    for (int n = 0; n < 4; ++n) sc[n] = (f32x4){0.f, 0.f, 0.f, 0.f};
    __builtin_amdgcn_s_setprio(1);
    #pragma unroll
    for (int kk = 0; kk < 2; ++kk) {
      #pragma unroll
      for (int n = 0; n < 4; ++n) {
        s16x8 kfr = *(const s16x8*)(&Ks[cur][(n * 16 + li) * LDK + kk * 32 + lg * 8]);
        sc[n] = __builtin_amdgcn_mfma_f32_16x16x32_bf16(kfr, qf[kk], sc[n], 0, 0, 0);
      }
    }
    __builtin_amdgcn_s_setprio(0);

    if (t == ntiles - 1) {            // diagonal tile: mask key > query
      const int qrel = w * 16 + li;
      #pragma unroll
      for (int n = 0; n < 4; ++n)
        #pragma unroll
        for (int r = 0; r < 4; ++r)
          if (n * 16 + lg * 4 + r > qrel) sc[n][r] = -1e9f;
    }

    // no-max softmax: P = exp2(S); pack to bf16 for PV (l comes from MFMA)
    #pragma unroll
    for (int n = 0; n < 4; ++n) {
      float p0 = exp2f(sc[n][0]);
      float p1 = exp2f(sc[n][1]);
      float p2 = exp2f(sc[n][2]);
      float p3 = exp2f(sc[n][3]);
      // fast bf16 pair-pack: +0x8000 round bias, v_perm selects hi16 halves
      unsigned a0 = __float_as_uint(p0) + 0x8000u;
      unsigned a1 = __float_as_uint(p1) + 0x8000u;
      unsigned a2 = __float_as_uint(p2) + 0x8000u;
      unsigned a3 = __float_as_uint(p3) + 0x8000u;
      uint2 wv;
      wv.x = __builtin_amdgcn_perm(a1, a0, 0x07060302u);  // hi16(a1)<<16 | hi16(a0)
      wv.y = __builtin_amdgcn_perm(a3, a2, 0x07060302u);
      *(uint2*)(&Ps[w][li * LDK + n * 16 + lg * 4]) = wv;
    }

    // O += P @ V ; l += P @ 1
    __builtin_amdgcn_s_setprio(1);
    #pragma unroll
    for (int kk = 0; kk < 2; ++kk) {
      s16x8 pf = *(const s16x8*)(&Ps[w][li * LDK + kk * 32 + lg * 8]);
      #pragma unroll
      for (int n = 0; n < 4; ++n) {
        s16x8 vf = *(const s16x8*)(&Vs[cur][(n * 16 + li) * LDK + kk * 32 + lg * 8]);
        o[n] = __builtin_amdgcn_mfma_f32_16x16x32_bf16(pf, vf, o[n], 0, 0, 0);
      }
      ol = __builtin_amdgcn_mfma_f32_16x16x32_bf16(pf, vones, ol, 0, 0, 0);
    }
    __builtin_amdgcn_s_setprio(0);

    if (more) {                       // write next tile into other buffer
      *(uint4*)(&Ks[cur ^ 1][row16 * LDK + col8])        = rKa;
      *(uint4*)(&Ks[cur ^ 1][(row16 + 32) * LDK + col8]) = rKb;
      *(uint4*)(&Vs[cur ^ 1][row16 * LDK + col8])        = rVa;
      *(uint4*)(&Vs[cur ^ 1][(row16 + 32) * LDK + col8]) = rVb;
      __syncthreads();
    }
  }

  // epilogue: attn[b][s][h*64+d] bf16 ; o row = q(lg*4+r), col = d(n*16+li)
  // ol[r] is l for q-row lg*4+r — same layout as o, no cross-lane needed.
  float linvq[4];
  #pragma unroll
  for (int r = 0; r < 4; ++r) linvq[r] = 1.0f / ol[r];
  #pragma unroll
  for (int n = 0; n < 4; ++n)
    #pragma unroll
    for (int r = 0; r < 4; ++r) {
      int srow = q0 + w * 16 + lg * 4 + r;
      attnOut[(size_t)(b * HS + srow) * HIDN + h * 64 + n * 16 + li] = f2bf(o[n][r] * linvq[r]);
    }
}

// ---------------- K3: output GEMM attn @ Wo -> fp32 d_out -------------------
// XCD-aware 1-D grid (256 blocks): XCD g owns m-tiles 4g..4g+3; n fastest.
__global__ __launch_bounds__(256) void k_out(const u16* __restrict__ A, const u16* __restrict__ Bt,
                                             float* __restrict__ out) {
  __shared__ __align__(16) u16 As[BM * 64];
  __shared__ __align__(16) u16 Bs[BN * 64];
  const int bid = blockIdx.x;
  const int g   = bid & 7;
  const int idx = bid >> 3;         // 0..31
  const int nt  = idx & 7;
  const int ml  = idx >> 3;         // 0..3
  const int mt  = g * 4 + ml;
  const int tid = threadIdx.x;
  const int lane = tid & 63, wave = tid >> 6;
  const int wr = wave >> 1, wc = wave & 1;
  const int lg = lane >> 4, li = lane & 15;
  const int bm0 = mt * BM, bn0 = nt * BN;

  const int srow = lane >> 3;
  const int scol = (lane & 7) * 8;

  f32x4 acc[4][4];
  #pragma unroll
  for (int m = 0; m < 4; ++m)
    #pragma unroll
    for (int n = 0; n < 4; ++n) acc[m][n] = (f32x4){0.f, 0.f, 0.f, 0.f};

  for (int k0 = 0; k0 < HIDN; k0 += BK) {
    __syncthreads();
    #pragma unroll
    for (int c = 0; c < 4; ++c) {
      const int ci = wave * 4 + c;
      const int row = ci * 8 + srow;
      gload16(A  + (size_t)(bm0 + row) * HIDN + k0 + scol, &As[ci * 512]);
      gload16(Bt + (size_t)(bn0 + row) * HIDN + k0 + scol, &Bs[ci * 512]);
    }
    __syncthreads();
    #pragma unroll
    for (int kk = 0; kk < 2; ++kk) {
      s16x8 af[4], bfr[4];
      #pragma unroll
      for (int m = 0; m < 4; ++m) af[m]  = *(const s16x8*)(&As[(wr * 64 + m * 16 + li) * 64 + kk * 32 + lg * 8]);
      #pragma unroll
      for (int n = 0; n < 4; ++n) bfr[n] = *(const s16x8*)(&Bs[(wc * 64 + n * 16 + li) * 64 + kk * 32 + lg * 8]);
      __builtin_amdgcn_s_setprio(1);
      #pragma unroll
      for (int m = 0; m < 4; ++m)
        #pragma unroll
        for (int n = 0; n < 4; ++n)
          acc[m][n] = __builtin_amdgcn_mfma_f32_16x16x32_bf16(af[m], bfr[n], acc[m][n], 0, 0, 0);
      __builtin_amdgcn_s_setprio(0);
    }
  }

  #pragma unroll
  for (int m = 0; m < 4; ++m)
    #pragma unroll
    for (int r = 0; r < 4; ++r) {
      int t = bm0 + wr * 64 + m * 16 + lg * 4 + r;
      #pragma unroll
      for (int n = 0; n < 4; ++n) {
        int c = bn0 + wc * 64 + n * 16 + li;
        out[(size_t)t * HIDN + c] = acc[m][n][r];
      }
    }
}

extern "C" void kernel_launch(void* const* d_in, const int* in_sizes, int n_in,
                              void* d_out, int out_size, void* d_ws, size_t ws_size,
                              hipStream_t stream) {
  const float* hs   = (const float*)d_in[0];
  const float* info = (const float*)d_in[1];
  const float* Wq   = (const float*)d_in[2];
  const float* Wk   = (const float*)d_in[3];
  const float* Wv   = (const float*)d_in[4];
  const float* Wo   = (const float*)d_in[5];
  float* out = (float*)d_out;

  char* ws = (char*)d_ws;
  u16* Xbf  = (u16*)(ws);                         // 8 MB, reused as attn buffer after K1
  u16* Wt   = (u16*)(ws + ((size_t)8  << 20));    // 8 MB: Wq^T,Wk^T,Wv^T,Wo^T bf16
  u16* Qb   = (u16*)(ws + ((size_t)16 << 20));    // 8 MB [B][H][S][D]
  u16* Kb   = (u16*)(ws + ((size_t)24 << 20));    // 8 MB [B][H][S][D]
  u16* Vt   = (u16*)(ws + ((size_t)32 << 20));    // 8 MB [B][H][D][S]
  u16* attn = Xbf;                                 // [4096][1024] bf16

  k_prep<<<dim3(1024 + MROWS * HIDN / 1024), 256, 0, stream>>>(hs, Wq, Wk, Wv, Wo, Wt, Xbf);
  k_qkv<<<dim3(768), 256, 0, stream>>>(Xbf, Wt, info, Qb, Kb, Vt);
  k_attn<<<dim3(1024), 256, 0, stream>>>(Qb, Kb, Vt, attn);
  k_out<<<dim3(256), 256, 0, stream>>>(attn, Wt + (size_t)3 * HIDN * HIDN, out);
}